// Round 1
// baseline (443.198 us; speedup 1.0000x reference)
//
#include <hip/hip_runtime.h>
#include <hip/hip_bf16.h>
#include <math.h>

#define NB 4096      // tokens
#define ND 1024      // model dim
#define NH 4096      // hidden dim
#define NE 8         // experts
#define NKK 2        // top-k
#define NROWS (NB*NKK)   // 8192 (token,slot) rows

typedef __attribute__((ext_vector_type(8))) short short8;
typedef __attribute__((ext_vector_type(4))) float f32x4;

__device__ __forceinline__ void gload_lds16(const void* g, void* l) {
    __builtin_amdgcn_global_load_lds(
        (const __attribute__((address_space(1))) unsigned int*)g,
        (__attribute__((address_space(3))) unsigned int*)l, 16, 0, 0);
}

__device__ __forceinline__ unsigned short f2bf(float f) {
    __hip_bfloat16 h = __float2bfloat16(f);
    return *reinterpret_cast<unsigned short*>(&h);
}

// ---------------- prep kernels ----------------

__global__ void k_cvt_x(const float* __restrict__ in, __hip_bfloat16* __restrict__ out, int n8) {
    int i = blockIdx.x * 256 + threadIdx.x;
    if (i >= n8) return;
    const float4* p = reinterpret_cast<const float4*>(in) + (size_t)i * 2;
    float4 a = p[0], b = p[1];
    ushort4 lo, hi;
    lo.x = f2bf(a.x); lo.y = f2bf(a.y); lo.z = f2bf(a.z); lo.w = f2bf(a.w);
    hi.x = f2bf(b.x); hi.y = f2bf(b.y); hi.z = f2bf(b.z); hi.w = f2bf(b.w);
    reinterpret_cast<ushort4*>(out)[(size_t)i*2]   = lo;
    reinterpret_cast<ushort4*>(out)[(size_t)i*2+1] = hi;
}

// in: [E][R][C] f32  ->  out: [E][C][R] bf16  (transpose + convert)
__global__ void k_transpose_cvt(const float* __restrict__ in, __hip_bfloat16* __restrict__ out,
                                int R, int C) {
    __shared__ float tile[64][65];
    const size_t ebase = (size_t)blockIdx.z * R * C;
    const int r0 = blockIdx.y * 64, c0 = blockIdx.x * 64;
    const int tx = threadIdx.x & 63, tg = threadIdx.x >> 6;
    #pragma unroll
    for (int i = 0; i < 16; ++i) {
        int r = tg + i * 4;
        tile[r][tx] = in[ebase + (size_t)(r0 + r) * C + (c0 + tx)];
    }
    __syncthreads();
    const int q = threadIdx.x & 15, cw = threadIdx.x >> 4;
    #pragma unroll
    for (int i = 0; i < 4; ++i) {
        int c = cw + i * 16;
        ushort4 v;
        v.x = f2bf(tile[q*4+0][c]);
        v.y = f2bf(tile[q*4+1][c]);
        v.z = f2bf(tile[q*4+2][c]);
        v.w = f2bf(tile[q*4+3][c]);
        *reinterpret_cast<ushort4*>(&out[ebase + (size_t)(c0 + c) * R + (r0 + q*4)]) = v;
    }
}

// ---------------- routing ----------------

__global__ void k_route_count(const int* __restrict__ idx, int* cnt) {
    int b = blockIdx.x * 256 + threadIdx.x;
    if (b < NB) {
        atomicAdd(&cnt[idx[2*b]], 1);
        atomicAdd(&cnt[idx[2*b+1]], 1);
    }
}

__global__ void k_route_scan(const int* __restrict__ cnt, int* offs, int* cursor) {
    if (threadIdx.x == 0) {
        int s = 0;
        for (int e = 0; e < NE; ++e) { offs[e] = s; cursor[e] = s; s += cnt[e]; }
        offs[NE] = s;
    }
}

__global__ void k_route_fill(const int* __restrict__ idx, const float* __restrict__ hw,
                             int* cursor, int* tok, float* gw) {
    int b = blockIdx.x * 256 + threadIdx.x;
    if (b < NB) {
        #pragma unroll
        for (int k = 0; k < NKK; ++k) {
            int e = idx[2*b + k];
            int p = atomicAdd(&cursor[e], 1);
            tok[p] = b;
            gw[p]  = hw[2*b + k];
        }
    }
}

// ---------------- grouped GEMM (128x128 tile, 4 waves, BK=64) ----------------
// STAGE 1: h = gelu(Xg @ w1t^T + b1)   (N=NH, K=ND), A rows gathered via tok[]
// STAGE 2: out += gw * (h @ w2t^T + b2) (N=ND, K=NH), atomic scatter to out

template<int STAGE>
__global__ __launch_bounds__(256, 2) void moe_gemm(
    const __hip_bfloat16* __restrict__ Asrc,
    const __hip_bfloat16* __restrict__ Bt,     // [E][N][K] bf16
    const float* __restrict__ bias,            // [E][N]
    __hip_bfloat16* __restrict__ Hout,
    float* __restrict__ Out,
    const int* __restrict__ offs,
    const int* __restrict__ tok,
    const float* __restrict__ gw)
{
    constexpr int N = (STAGE == 1) ? NH : ND;
    constexpr int K = (STAGE == 1) ? ND : NH;

    const int e = blockIdx.z;
    const int end = offs[e + 1];
    const int rowbase = offs[e] + blockIdx.y * 128;
    if (rowbase >= end) return;
    const int nt = blockIdx.x;

    __shared__ __align__(16) __hip_bfloat16 sA[128 * 64];
    __shared__ __align__(16) __hip_bfloat16 sB[128 * 64];

    const int tid = threadIdx.x;
    const int w = tid >> 6;
    const int l = tid & 63;

    // --- staging setup: pre-swizzled per-lane global sources, linear LDS dest ---
    const int srow = tid >> 3;                   // 0..31 (+ i*32)
    const int schunk = (tid & 7) ^ (srow & 7);   // XOR-swizzled source 16B chunk
    const __hip_bfloat16* aptr[4];
    const __hip_bfloat16* bptr[4];
    #pragma unroll
    for (int i = 0; i < 4; ++i) {
        int r = srow + i * 32;
        int re = rowbase + r; if (re > end - 1) re = end - 1;
        if (STAGE == 1) aptr[i] = Asrc + (size_t)tok[re] * ND + schunk * 8;
        else            aptr[i] = Asrc + (size_t)re * NH + schunk * 8;
        bptr[i] = Bt + ((size_t)e * N + (nt * 128 + r)) * K + schunk * 8;
    }
    __hip_bfloat16 *adst[4], *bdst[4];
    #pragma unroll
    for (int i = 0; i < 4; ++i) {
        adst[i] = sA + (i * 256 + w * 64) * 8;   // wave-uniform, linear
        bdst[i] = sB + (i * 256 + w * 64) * 8;
    }

    const int wm = (w >> 1) * 64;
    const int wn = (w & 1) * 64;
    const int l15 = l & 15, l4 = l >> 4;

    f32x4 acc[4][4];
    #pragma unroll
    for (int mi = 0; mi < 4; ++mi)
        #pragma unroll
        for (int ni = 0; ni < 4; ++ni) acc[mi][ni] = (f32x4){0.f, 0.f, 0.f, 0.f};

    // swizzled ds_read byte offsets
    int aoff[4][2], boff[4][2];
    #pragma unroll
    for (int mi = 0; mi < 4; ++mi) {
        int row = wm + mi * 16 + l15;
        #pragma unroll
        for (int ks = 0; ks < 2; ++ks)
            aoff[mi][ks] = row * 128 + (((ks * 4 + l4) ^ (row & 7)) * 16);
    }
    #pragma unroll
    for (int ni = 0; ni < 4; ++ni) {
        int row = wn + ni * 16 + l15;
        #pragma unroll
        for (int ks = 0; ks < 2; ++ks)
            boff[ni][ks] = row * 128 + (((ks * 4 + l4) ^ (row & 7)) * 16);
    }

    const char* sAb = (const char*)sA;
    const char* sBb = (const char*)sB;

    for (int kt = 0; kt < K / 64; ++kt) {
        #pragma unroll
        for (int i = 0; i < 4; ++i) {
            gload_lds16(aptr[i] + kt * 64, adst[i]);
            gload_lds16(bptr[i] + kt * 64, bdst[i]);
        }
        __syncthreads();
        short8 af[4][2], bfr[4][2];
        #pragma unroll
        for (int mi = 0; mi < 4; ++mi)
            #pragma unroll
            for (int ks = 0; ks < 2; ++ks)
                af[mi][ks] = *(const short8*)(sAb + aoff[mi][ks]);
        #pragma unroll
        for (int ni = 0; ni < 4; ++ni)
            #pragma unroll
            for (int ks = 0; ks < 2; ++ks)
                bfr[ni][ks] = *(const short8*)(sBb + boff[ni][ks]);
        #pragma unroll
        for (int mi = 0; mi < 4; ++mi)
            #pragma unroll
            for (int ni = 0; ni < 4; ++ni)
                #pragma unroll
                for (int ks = 0; ks < 2; ++ks)
                    acc[mi][ni] = __builtin_amdgcn_mfma_f32_16x16x32_bf16(
                        af[mi][ks], bfr[ni][ks], acc[mi][ni], 0, 0, 0);
        __syncthreads();
    }

    // --- epilogue --- C/D layout: col = lane&15, row = (lane>>4)*4 + j  [m89]
    const int ncol0 = nt * 128 + wn;
    #pragma unroll
    for (int mi = 0; mi < 4; ++mi) {
        #pragma unroll
        for (int ni = 0; ni < 4; ++ni) {
            int gn = ncol0 + ni * 16 + l15;
            float bv = bias[e * N + gn];
            #pragma unroll
            for (int j = 0; j < 4; ++j) {
                int re = rowbase + wm + mi * 16 + l4 * 4 + j;
                if (re < end) {
                    float v = acc[mi][ni][j] + bv;
                    if (STAGE == 1) {
                        float g = 0.5f * v * (1.0f + erff(v * 0.70710678118654752f));
                        Hout[(size_t)re * NH + gn] = __float2bfloat16(g);
                    } else {
                        atomicAdd(&Out[(size_t)tok[re] * ND + gn], gw[re] * v);
                    }
                }
            }
        }
    }
}

// ---------------- launch ----------------

extern "C" void kernel_launch(void* const* d_in, const int* in_sizes, int n_in,
                              void* d_out, int out_size, void* d_ws, size_t ws_size,
                              hipStream_t stream) {
    const float* x   = (const float*)d_in[0];
    const int*   idx = (const int*)d_in[1];
    const float* hw  = (const float*)d_in[2];
    const float* w1  = (const float*)d_in[3];
    const float* b1  = (const float*)d_in[4];
    const float* w2  = (const float*)d_in[5];
    const float* b2  = (const float*)d_in[6];
    float* out = (float*)d_out;

    char* ws = (char*)d_ws;
    size_t off = 0;
    __hip_bfloat16* xb  = (__hip_bfloat16*)(ws + off); off += (size_t)NB * ND * 2;
    __hip_bfloat16* w1t = (__hip_bfloat16*)(ws + off); off += (size_t)NE * ND * NH * 2;
    __hip_bfloat16* w2t = (__hip_bfloat16*)(ws + off); off += (size_t)NE * NH * ND * 2;
    __hip_bfloat16* h   = (__hip_bfloat16*)(ws + off); off += (size_t)NROWS * NH * 2;
    int*   tok    = (int*)(ws + off);   off += NROWS * 4;
    float* gwb    = (float*)(ws + off); off += NROWS * 4;
    int*   cnt    = (int*)(ws + off);   off += 16 * 4;
    int*   offs   = (int*)(ws + off);   off += 16 * 4;
    int*   cursor = (int*)(ws + off);   off += 16 * 4;
    (void)ws_size; (void)in_sizes; (void)n_in; (void)out_size;

    hipMemsetAsync(d_out, 0, (size_t)NB * ND * sizeof(float), stream);
    hipMemsetAsync(cnt, 0, 16 * 4, stream);

    k_cvt_x<<<dim3((NB * ND / 8 + 255) / 256), 256, 0, stream>>>(x, xb, NB * ND / 8);
    k_transpose_cvt<<<dim3(NH / 64, ND / 64, NE), 256, 0, stream>>>(w1, w1t, ND, NH);
    k_transpose_cvt<<<dim3(ND / 64, NH / 64, NE), 256, 0, stream>>>(w2, w2t, NH, ND);
    k_route_count<<<dim3((NB + 255) / 256), 256, 0, stream>>>(idx, cnt);
    k_route_scan<<<1, 64, 0, stream>>>(cnt, offs, cursor);
    k_route_fill<<<dim3((NB + 255) / 256), 256, 0, stream>>>(idx, hw, cursor, tok, gwb);

    moe_gemm<1><<<dim3(NH / 128, NROWS / 128, NE), 256, 0, stream>>>(
        xb, w1t, b1, h, nullptr, offs, tok, gwb);
    moe_gemm<2><<<dim3(ND / 128, NROWS / 128, NE), 256, 0, stream>>>(
        h, w2t, b2, nullptr, out, offs, tok, gwb);
}

// Round 2
// 416.745 us; speedup vs baseline: 1.0635x; 1.0635x over previous
//
#include <hip/hip_runtime.h>
#include <hip/hip_bf16.h>
#include <math.h>

#define NB 4096      // tokens
#define ND 1024      // model dim
#define NH 4096      // hidden dim
#define NE 8         // experts
#define NKK 2        // top-k
#define NROWS (NB*NKK)   // 8192 (token,slot) rows
#define MAXT 72          // max row-tiles: 64 + 8 partial

typedef __attribute__((ext_vector_type(8))) short short8;
typedef __attribute__((ext_vector_type(4))) float f32x4;

__device__ __forceinline__ void gload_lds16(const void* g, void* l) {
    __builtin_amdgcn_global_load_lds(
        (const __attribute__((address_space(1))) unsigned int*)g,
        (__attribute__((address_space(3))) unsigned int*)l, 16, 0, 0);
}

__device__ __forceinline__ unsigned short f2bf(float f) {
    __hip_bfloat16 h = __float2bfloat16(f);
    return *reinterpret_cast<unsigned short*>(&h);
}

// exact-gelu via A&S 7.1.26 erf approx (|erf err| < 1.5e-7), hw exp/rcp
__device__ __forceinline__ float fast_gelu(float x) {
    float xs  = x * 0.70710678118654752f;
    float axs = fabsf(xs);
    float t   = __builtin_amdgcn_rcpf(1.0f + 0.3275911f * axs);
    float p   = t * (0.254829592f + t * (-0.284496736f + t * (1.421413741f +
                t * (-1.453152027f + t * 1.061405429f))));
    float e   = __expf(-xs * xs);
    float erf_abs = 1.0f - p * e;
    float erf = copysignf(erf_abs, x);
    return 0.5f * x * (1.0f + erf);
}

// ---------------- prep kernels ----------------

__global__ void k_cvt_x(const float* __restrict__ in, __hip_bfloat16* __restrict__ out, int n8) {
    int i = blockIdx.x * 256 + threadIdx.x;
    if (i >= n8) return;
    const float4* p = reinterpret_cast<const float4*>(in) + (size_t)i * 2;
    float4 a = p[0], b = p[1];
    ushort4 lo, hi;
    lo.x = f2bf(a.x); lo.y = f2bf(a.y); lo.z = f2bf(a.z); lo.w = f2bf(a.w);
    hi.x = f2bf(b.x); hi.y = f2bf(b.y); hi.z = f2bf(b.z); hi.w = f2bf(b.w);
    reinterpret_cast<ushort4*>(out)[(size_t)i*2]   = lo;
    reinterpret_cast<ushort4*>(out)[(size_t)i*2+1] = hi;
}

// in: [E][R][C] f32  ->  out: [E][C][R] bf16  (transpose + convert)
__global__ void k_transpose_cvt(const float* __restrict__ in, __hip_bfloat16* __restrict__ out,
                                int R, int C) {
    __shared__ float tile[64][65];
    const size_t ebase = (size_t)blockIdx.z * R * C;
    const int r0 = blockIdx.y * 64, c0 = blockIdx.x * 64;
    const int tx = threadIdx.x & 63, tg = threadIdx.x >> 6;
    #pragma unroll
    for (int i = 0; i < 16; ++i) {
        int r = tg + i * 4;
        tile[r][tx] = in[ebase + (size_t)(r0 + r) * C + (c0 + tx)];
    }
    __syncthreads();
    const int q = threadIdx.x & 15, cw = threadIdx.x >> 4;
    #pragma unroll
    for (int i = 0; i < 4; ++i) {
        int c = cw + i * 16;
        ushort4 v;
        v.x = f2bf(tile[q*4+0][c]);
        v.y = f2bf(tile[q*4+1][c]);
        v.z = f2bf(tile[q*4+2][c]);
        v.w = f2bf(tile[q*4+3][c]);
        *reinterpret_cast<ushort4*>(&out[ebase + (size_t)(c0 + c) * R + (r0 + q*4)]) = v;
    }
}

// ---------------- routing ----------------

__global__ void k_route_count(const int* __restrict__ idx, int* cnt) {
    int b = blockIdx.x * 256 + threadIdx.x;
    if (b < NB) {
        atomicAdd(&cnt[idx[2*b]], 1);
        atomicAdd(&cnt[idx[2*b+1]], 1);
    }
}

// builds prefix offsets + expert-pure row-tile list
__global__ void k_route_scan(const int* __restrict__ cnt, int* offs, int* cursor,
                             int* tile_e, int* tile_row, int* ntiles) {
    if (threadIdx.x == 0) {
        int s = 0, t = 0;
        for (int e = 0; e < NE; ++e) {
            offs[e] = s; cursor[e] = s;
            for (int r = 0; r < cnt[e]; r += 128) {
                tile_e[t] = e; tile_row[t] = s + r; ++t;
            }
            s += cnt[e];
        }
        offs[NE] = s;
        *ntiles = t;
    }
}

__global__ void k_route_fill(const int* __restrict__ idx, const float* __restrict__ hw,
                             int* cursor, int* tok, float* gw) {
    int b = blockIdx.x * 256 + threadIdx.x;
    if (b < NB) {
        #pragma unroll
        for (int k = 0; k < NKK; ++k) {
            int e = idx[2*b + k];
            int p = atomicAdd(&cursor[e], 1);
            tok[p] = b;
            gw[p]  = hw[2*b + k];
        }
    }
}

// ---------------- grouped GEMM (128x128 tile, 4 waves, BK=64) ----------------
// STAGE 1: h = gelu(Xg @ w1t^T + b1)   (N=NH, K=ND), A rows gathered via tok[]
// STAGE 2: out += gw * (h @ w2t^T + b2) (N=ND, K=NH), atomic scatter to out
// 1D grid, logical = nt*MAXT + tile (tile fastest => consecutive blocks share
// the (e,nt) weight panel), bijective XCD swizzle for L2 locality.

template<int STAGE>
__global__ __launch_bounds__(256, 4) void moe_gemm(
    const __hip_bfloat16* __restrict__ Asrc,
    const __hip_bfloat16* __restrict__ Bt,     // [E][N][K] bf16
    const float* __restrict__ bias,            // [E][N]
    __hip_bfloat16* __restrict__ Hout,
    float* __restrict__ Out,
    const int* __restrict__ offs,
    const int* __restrict__ tok,
    const float* __restrict__ gw,
    const int* __restrict__ tile_e,
    const int* __restrict__ tile_row,
    const int* __restrict__ ntiles)
{
    constexpr int N = (STAGE == 1) ? NH : ND;
    constexpr int K = (STAGE == 1) ? ND : NH;
    constexpr int NT_N = N / 128;
    constexpr int TOTAL = NT_N * MAXT;
    constexpr int CPX = TOTAL / 8;

    // bijective XCD swizzle: each XCD gets a contiguous logical chunk
    const int bid = blockIdx.x;
    const int wgid = (bid & 7) * CPX + (bid >> 3);
    const int tile = wgid % MAXT;
    const int nt   = wgid / MAXT;
    if (tile >= *ntiles) return;

    const int e = tile_e[tile];
    const int rowbase = tile_row[tile];
    const int end = offs[e + 1];

    __shared__ __align__(16) __hip_bfloat16 sA[128 * 64];
    __shared__ __align__(16) __hip_bfloat16 sB[128 * 64];

    const int tid = threadIdx.x;
    const int w = tid >> 6;
    const int l = tid & 63;

    // --- staging setup: pre-swizzled per-lane global sources, linear LDS dest ---
    const int srow = tid >> 3;                   // 0..31 (+ i*32)
    const int schunk = (tid & 7) ^ (srow & 7);   // XOR-swizzled source 16B chunk
    const __hip_bfloat16* aptr[4];
    const __hip_bfloat16* bptr[4];
    #pragma unroll
    for (int i = 0; i < 4; ++i) {
        int r = srow + i * 32;
        int re = rowbase + r; if (re > end - 1) re = end - 1;
        if (STAGE == 1) aptr[i] = Asrc + (size_t)tok[re] * ND + schunk * 8;
        else            aptr[i] = Asrc + (size_t)re * NH + schunk * 8;
        bptr[i] = Bt + ((size_t)e * N + (nt * 128 + r)) * K + schunk * 8;
    }
    __hip_bfloat16 *adst[4], *bdst[4];
    #pragma unroll
    for (int i = 0; i < 4; ++i) {
        adst[i] = sA + (i * 256 + w * 64) * 8;   // wave-uniform, linear
        bdst[i] = sB + (i * 256 + w * 64) * 8;
    }

    const int wm = (w >> 1) * 64;
    const int wn = (w & 1) * 64;
    const int l15 = l & 15, l4 = l >> 4;

    f32x4 acc[4][4];
    #pragma unroll
    for (int mi = 0; mi < 4; ++mi)
        #pragma unroll
        for (int ni = 0; ni < 4; ++ni) acc[mi][ni] = (f32x4){0.f, 0.f, 0.f, 0.f};

    // swizzled ds_read byte offsets
    int aoff[4][2], boff[4][2];
    #pragma unroll
    for (int mi = 0; mi < 4; ++mi) {
        int row = wm + mi * 16 + l15;
        #pragma unroll
        for (int ks = 0; ks < 2; ++ks)
            aoff[mi][ks] = row * 128 + (((ks * 4 + l4) ^ (row & 7)) * 16);
    }
    #pragma unroll
    for (int ni = 0; ni < 4; ++ni) {
        int row = wn + ni * 16 + l15;
        #pragma unroll
        for (int ks = 0; ks < 2; ++ks)
            boff[ni][ks] = row * 128 + (((ks * 4 + l4) ^ (row & 7)) * 16);
    }

    const char* sAb = (const char*)sA;
    const char* sBb = (const char*)sB;

    for (int kt = 0; kt < K / 64; ++kt) {
        #pragma unroll
        for (int i = 0; i < 4; ++i) {
            gload_lds16(aptr[i] + kt * 64, adst[i]);
            gload_lds16(bptr[i] + kt * 64, bdst[i]);
        }
        __syncthreads();
        short8 af[4][2], bfr[4][2];
        #pragma unroll
        for (int mi = 0; mi < 4; ++mi)
            #pragma unroll
            for (int ks = 0; ks < 2; ++ks)
                af[mi][ks] = *(const short8*)(sAb + aoff[mi][ks]);
        #pragma unroll
        for (int ni = 0; ni < 4; ++ni)
            #pragma unroll
            for (int ks = 0; ks < 2; ++ks)
                bfr[ni][ks] = *(const short8*)(sBb + boff[ni][ks]);
        #pragma unroll
        for (int mi = 0; mi < 4; ++mi)
            #pragma unroll
            for (int ni = 0; ni < 4; ++ni)
                #pragma unroll
                for (int ks = 0; ks < 2; ++ks)
                    acc[mi][ni] = __builtin_amdgcn_mfma_f32_16x16x32_bf16(
                        af[mi][ks], bfr[ni][ks], acc[mi][ni], 0, 0, 0);
        __syncthreads();
    }

    // --- epilogue --- C/D layout: col = lane&15, row = (lane>>4)*4 + j  [m89]
    const int ncol0 = nt * 128 + wn;
    #pragma unroll
    for (int mi = 0; mi < 4; ++mi) {
        #pragma unroll
        for (int ni = 0; ni < 4; ++ni) {
            int gn = ncol0 + ni * 16 + l15;
            float bv = bias[e * N + gn];
            #pragma unroll
            for (int j = 0; j < 4; ++j) {
                int re = rowbase + wm + mi * 16 + l4 * 4 + j;
                if (re < end) {
                    float v = acc[mi][ni][j] + bv;
                    if (STAGE == 1) {
                        Hout[(size_t)re * NH + gn] = __float2bfloat16(fast_gelu(v));
                    } else {
                        atomicAdd(&Out[(size_t)tok[re] * ND + gn], gw[re] * v);
                    }
                }
            }
        }
    }
}

// ---------------- launch ----------------

extern "C" void kernel_launch(void* const* d_in, const int* in_sizes, int n_in,
                              void* d_out, int out_size, void* d_ws, size_t ws_size,
                              hipStream_t stream) {
    const float* x   = (const float*)d_in[0];
    const int*   idx = (const int*)d_in[1];
    const float* hw  = (const float*)d_in[2];
    const float* w1  = (const float*)d_in[3];
    const float* b1  = (const float*)d_in[4];
    const float* w2  = (const float*)d_in[5];
    const float* b2  = (const float*)d_in[6];
    float* out = (float*)d_out;

    char* ws = (char*)d_ws;
    size_t off = 0;
    __hip_bfloat16* xb  = (__hip_bfloat16*)(ws + off); off += (size_t)NB * ND * 2;
    __hip_bfloat16* w1t = (__hip_bfloat16*)(ws + off); off += (size_t)NE * ND * NH * 2;
    __hip_bfloat16* w2t = (__hip_bfloat16*)(ws + off); off += (size_t)NE * NH * ND * 2;
    __hip_bfloat16* h   = (__hip_bfloat16*)(ws + off); off += (size_t)NROWS * NH * 2;
    int*   tok     = (int*)(ws + off);   off += NROWS * 4;
    float* gwb     = (float*)(ws + off); off += NROWS * 4;
    int*   cnt     = (int*)(ws + off);   off += 16 * 4;
    int*   offs    = (int*)(ws + off);   off += 16 * 4;
    int*   cursor  = (int*)(ws + off);   off += 16 * 4;
    int*   tile_e  = (int*)(ws + off);   off += MAXT * 4;
    int*   tile_row= (int*)(ws + off);   off += MAXT * 4;
    int*   ntiles  = (int*)(ws + off);   off += 16 * 4;
    (void)ws_size; (void)in_sizes; (void)n_in; (void)out_size;

    hipMemsetAsync(d_out, 0, (size_t)NB * ND * sizeof(float), stream);
    hipMemsetAsync(cnt, 0, 16 * 4, stream);

    k_cvt_x<<<dim3((NB * ND / 8 + 255) / 256), 256, 0, stream>>>(x, xb, NB * ND / 8);
    k_transpose_cvt<<<dim3(NH / 64, ND / 64, NE), 256, 0, stream>>>(w1, w1t, ND, NH);
    k_transpose_cvt<<<dim3(ND / 64, NH / 64, NE), 256, 0, stream>>>(w2, w2t, NH, ND);
    k_route_count<<<dim3((NB + 255) / 256), 256, 0, stream>>>(idx, cnt);
    k_route_scan<<<1, 64, 0, stream>>>(cnt, offs, cursor, tile_e, tile_row, ntiles);
    k_route_fill<<<dim3((NB + 255) / 256), 256, 0, stream>>>(idx, hw, cursor, tok, gwb);

    moe_gemm<1><<<dim3((NH / 128) * MAXT), 256, 0, stream>>>(
        xb, w1t, b1, h, nullptr, offs, tok, gwb, tile_e, tile_row, ntiles);
    moe_gemm<2><<<dim3((ND / 128) * MAXT), 256, 0, stream>>>(
        h, w2t, b2, nullptr, out, offs, tok, gwb, tile_e, tile_row, ntiles);
}

// Round 3
// 404.529 us; speedup vs baseline: 1.0956x; 1.0302x over previous
//
#include <hip/hip_runtime.h>
#include <hip/hip_bf16.h>
#include <math.h>

#define NB 4096      // tokens
#define ND 1024      // model dim
#define NH 4096      // hidden dim
#define NE 8         // experts
#define NKK 2        // top-k
#define NROWS (NB*NKK)   // 8192 (token,slot) rows
#define MAXT 72          // max row-tiles: 64 + 8 partial (8 tile-blocks of 9)

typedef __attribute__((ext_vector_type(8))) short short8;
typedef __attribute__((ext_vector_type(4))) float f32x4;

__device__ __forceinline__ void gload_lds16(const void* g, void* l) {
    __builtin_amdgcn_global_load_lds(
        (const __attribute__((address_space(1))) unsigned int*)g,
        (__attribute__((address_space(3))) unsigned int*)l, 16, 0, 0);
}

__device__ __forceinline__ unsigned short f2bf(float f) {
    __hip_bfloat16 h = __float2bfloat16(f);
    return *reinterpret_cast<unsigned short*>(&h);
}

// exact-gelu via A&S 7.1.26 erf approx (|erf err| < 1.5e-7), hw exp/rcp
__device__ __forceinline__ float fast_gelu(float x) {
    float xs  = x * 0.70710678118654752f;
    float axs = fabsf(xs);
    float t   = __builtin_amdgcn_rcpf(1.0f + 0.3275911f * axs);
    float p   = t * (0.254829592f + t * (-0.284496736f + t * (1.421413741f +
                t * (-1.453152027f + t * 1.061405429f))));
    float e   = __expf(-xs * xs);
    float erf_abs = 1.0f - p * e;
    float erf = copysignf(erf_abs, x);
    return 0.5f * x * (1.0f + erf);
}

// ---------------- prep kernels ----------------

__global__ void k_cvt_x(const float* __restrict__ in, __hip_bfloat16* __restrict__ out, int n8) {
    int i = blockIdx.x * 256 + threadIdx.x;
    if (i >= n8) return;
    const float4* p = reinterpret_cast<const float4*>(in) + (size_t)i * 2;
    float4 a = p[0], b = p[1];
    ushort4 lo, hi;
    lo.x = f2bf(a.x); lo.y = f2bf(a.y); lo.z = f2bf(a.z); lo.w = f2bf(a.w);
    hi.x = f2bf(b.x); hi.y = f2bf(b.y); hi.z = f2bf(b.z); hi.w = f2bf(b.w);
    reinterpret_cast<ushort4*>(out)[(size_t)i*2]   = lo;
    reinterpret_cast<ushort4*>(out)[(size_t)i*2+1] = hi;
}

// in: [E][R][C] f32  ->  out: [E][C][R] bf16  (transpose + convert)
// float4 loads (16B/lane), LDS pad 68 keeps float4 stores 16B-aligned,
// read side is 2-way bank aliasing (free).
__global__ void k_transpose_cvt(const float* __restrict__ in, __hip_bfloat16* __restrict__ out,
                                int R, int C) {
    __shared__ float tile[64][68];
    const size_t ebase = (size_t)blockIdx.z * R * C;
    const int r0 = blockIdx.y * 64, c0 = blockIdx.x * 64;
    const int t = threadIdx.x;
    const int lr = t >> 4, lc4 = (t & 15) * 4;
    #pragma unroll
    for (int i = 0; i < 4; ++i) {
        int r = lr + i * 16;
        float4 v = *reinterpret_cast<const float4*>(&in[ebase + (size_t)(r0 + r) * C + (c0 + lc4)]);
        *reinterpret_cast<float4*>(&tile[r][lc4]) = v;
    }
    __syncthreads();
    const int q = t & 15, cw = t >> 4;
    #pragma unroll
    for (int i = 0; i < 4; ++i) {
        int cc = cw + i * 16;
        ushort4 v;
        v.x = f2bf(tile[q*4+0][cc]);
        v.y = f2bf(tile[q*4+1][cc]);
        v.z = f2bf(tile[q*4+2][cc]);
        v.w = f2bf(tile[q*4+3][cc]);
        *reinterpret_cast<ushort4*>(&out[ebase + (size_t)(c0 + cc) * R + (r0 + q*4)]) = v;
    }
}

// ---------------- routing ----------------

__global__ void k_route_count(const int* __restrict__ idx, int* cnt) {
    int b = blockIdx.x * 256 + threadIdx.x;
    if (b < NB) {
        atomicAdd(&cnt[idx[2*b]], 1);
        atomicAdd(&cnt[idx[2*b+1]], 1);
    }
}

// builds prefix offsets + expert-pure row-tile list
__global__ void k_route_scan(const int* __restrict__ cnt, int* offs, int* cursor,
                             int* tile_e, int* tile_row, int* ntiles) {
    if (threadIdx.x == 0) {
        int s = 0, t = 0;
        for (int e = 0; e < NE; ++e) {
            offs[e] = s; cursor[e] = s;
            for (int r = 0; r < cnt[e]; r += 128) {
                tile_e[t] = e; tile_row[t] = s + r; ++t;
            }
            s += cnt[e];
        }
        offs[NE] = s;
        *ntiles = t;
    }
}

__global__ void k_route_fill(const int* __restrict__ idx, const float* __restrict__ hw,
                             int* cursor, int* tok, float* gw) {
    int b = blockIdx.x * 256 + threadIdx.x;
    if (b < NB) {
        #pragma unroll
        for (int k = 0; k < NKK; ++k) {
            int e = idx[2*b + k];
            int p = atomicAdd(&cursor[e], 1);
            tok[p] = b;
            gw[p]  = hw[2*b + k];
        }
    }
}

// ---------------- grouped GEMM (128x128 tile, 4 waves, BK=64) ----------------
// STAGE 1: h = gelu(Xg @ w1t^T + b1)   (N=NH, K=ND), A rows gathered via tok[]
// STAGE 2: out += gw * (h @ w2t^T + b2) (N=ND, K=NH), atomic scatter to out
//
// Block->work mapping: XCD = bid&7 (HW round-robin). Each XCD owns NTL
// consecutive nt values. Within the XCD chunk, iterate as
//   for tile_block (9 tiles, ~2.25MB of A): for ntl: for tile-in-block
// so the A tile-block stays L2-resident across the NTL nt-sweeps, and the
// weight panel (e,nt) is shared by ~9 consecutive blocks on the same XCD.

template<int STAGE>
__global__ __launch_bounds__(256, 4) void moe_gemm(
    const __hip_bfloat16* __restrict__ Asrc,
    const __hip_bfloat16* __restrict__ Bt,     // [E][N][K] bf16
    const float* __restrict__ bias,            // [E][N]
    __hip_bfloat16* __restrict__ Hout,
    float* __restrict__ Out,
    const int* __restrict__ offs,
    const int* __restrict__ tok,
    const float* __restrict__ gw,
    const int* __restrict__ tile_e,
    const int* __restrict__ tile_row,
    const int* __restrict__ ntiles)
{
    constexpr int N = (STAGE == 1) ? NH : ND;
    constexpr int K = (STAGE == 1) ? ND : NH;
    constexpr int NT_N = N / 128;
    constexpr int NTL = NT_N / 8;          // nt values per XCD
    constexpr int TOTAL = NT_N * MAXT;

    const int bid = blockIdx.x;
    const int xcd = bid & 7;
    const int c = bid >> 3;                 // [0, TOTAL/8)
    const int tb  = c / (NTL * 9);
    const int rr  = c % (NTL * 9);
    const int ntl = rr / 9;
    const int tin = rr % 9;
    const int tile = tb * 9 + tin;
    const int nt = xcd * NTL + ntl;
    if (tile >= *ntiles) return;

    const int e = tile_e[tile];
    const int rowbase = tile_row[tile];
    const int end = offs[e + 1];

    __shared__ __align__(16) __hip_bfloat16 sA[128 * 64];
    __shared__ __align__(16) __hip_bfloat16 sB[128 * 64];

    const int tid = threadIdx.x;
    const int w = tid >> 6;
    const int l = tid & 63;

    // --- staging setup: pre-swizzled per-lane global sources, linear LDS dest ---
    const int srow = tid >> 3;                   // 0..31 (+ i*32)
    const int schunk = (tid & 7) ^ (srow & 7);   // XOR-swizzled source 16B chunk
    const __hip_bfloat16* aptr[4];
    const __hip_bfloat16* bptr[4];
    #pragma unroll
    for (int i = 0; i < 4; ++i) {
        int r = srow + i * 32;
        int re = rowbase + r; if (re > end - 1) re = end - 1;
        if (STAGE == 1) aptr[i] = Asrc + (size_t)tok[re] * ND + schunk * 8;
        else            aptr[i] = Asrc + (size_t)re * NH + schunk * 8;
        bptr[i] = Bt + ((size_t)e * N + (nt * 128 + r)) * K + schunk * 8;
    }
    __hip_bfloat16 *adst[4], *bdst[4];
    #pragma unroll
    for (int i = 0; i < 4; ++i) {
        adst[i] = sA + (i * 256 + w * 64) * 8;   // wave-uniform, linear
        bdst[i] = sB + (i * 256 + w * 64) * 8;
    }

    const int wm = (w >> 1) * 64;
    const int wn = (w & 1) * 64;
    const int l15 = l & 15, l4 = l >> 4;

    f32x4 acc[4][4];
    #pragma unroll
    for (int mi = 0; mi < 4; ++mi)
        #pragma unroll
        for (int ni = 0; ni < 4; ++ni) acc[mi][ni] = (f32x4){0.f, 0.f, 0.f, 0.f};

    // swizzled ds_read byte offsets
    int aoff[4][2], boff[4][2];
    #pragma unroll
    for (int mi = 0; mi < 4; ++mi) {
        int row = wm + mi * 16 + l15;
        #pragma unroll
        for (int ks = 0; ks < 2; ++ks)
            aoff[mi][ks] = row * 128 + (((ks * 4 + l4) ^ (row & 7)) * 16);
    }
    #pragma unroll
    for (int ni = 0; ni < 4; ++ni) {
        int row = wn + ni * 16 + l15;
        #pragma unroll
        for (int ks = 0; ks < 2; ++ks)
            boff[ni][ks] = row * 128 + (((ks * 4 + l4) ^ (row & 7)) * 16);
    }

    const char* sAb = (const char*)sA;
    const char* sBb = (const char*)sB;

    for (int kt = 0; kt < K / 64; ++kt) {
        #pragma unroll
        for (int i = 0; i < 4; ++i) {
            gload_lds16(aptr[i] + kt * 64, adst[i]);
            gload_lds16(bptr[i] + kt * 64, bdst[i]);
        }
        __syncthreads();
        short8 af[4][2], bfr[4][2];
        #pragma unroll
        for (int mi = 0; mi < 4; ++mi)
            #pragma unroll
            for (int ks = 0; ks < 2; ++ks)
                af[mi][ks] = *(const short8*)(sAb + aoff[mi][ks]);
        #pragma unroll
        for (int ni = 0; ni < 4; ++ni)
            #pragma unroll
            for (int ks = 0; ks < 2; ++ks)
                bfr[ni][ks] = *(const short8*)(sBb + boff[ni][ks]);
        #pragma unroll
        for (int mi = 0; mi < 4; ++mi)
            #pragma unroll
            for (int ni = 0; ni < 4; ++ni)
                #pragma unroll
                for (int ks = 0; ks < 2; ++ks)
                    acc[mi][ni] = __builtin_amdgcn_mfma_f32_16x16x32_bf16(
                        af[mi][ks], bfr[ni][ks], acc[mi][ni], 0, 0, 0);
        __syncthreads();
    }

    // --- epilogue --- C/D layout: col = lane&15, row = (lane>>4)*4 + j  [m89]
    const int ncol0 = nt * 128 + wn;
    #pragma unroll
    for (int mi = 0; mi < 4; ++mi) {
        #pragma unroll
        for (int ni = 0; ni < 4; ++ni) {
            int gn = ncol0 + ni * 16 + l15;
            float bv = bias[e * N + gn];
            #pragma unroll
            for (int j = 0; j < 4; ++j) {
                int re = rowbase + wm + mi * 16 + l4 * 4 + j;
                if (re < end) {
                    float v = acc[mi][ni][j] + bv;
                    if (STAGE == 1) {
                        Hout[(size_t)re * NH + gn] = __float2bfloat16(fast_gelu(v));
                    } else {
                        atomicAdd(&Out[(size_t)tok[re] * ND + gn], gw[re] * v);
                    }
                }
            }
        }
    }
}

// ---------------- launch ----------------

extern "C" void kernel_launch(void* const* d_in, const int* in_sizes, int n_in,
                              void* d_out, int out_size, void* d_ws, size_t ws_size,
                              hipStream_t stream) {
    const float* x   = (const float*)d_in[0];
    const int*   idx = (const int*)d_in[1];
    const float* hw  = (const float*)d_in[2];
    const float* w1  = (const float*)d_in[3];
    const float* b1  = (const float*)d_in[4];
    const float* w2  = (const float*)d_in[5];
    const float* b2  = (const float*)d_in[6];
    float* out = (float*)d_out;

    char* ws = (char*)d_ws;
    size_t off = 0;
    __hip_bfloat16* xb  = (__hip_bfloat16*)(ws + off); off += (size_t)NB * ND * 2;
    __hip_bfloat16* w1t = (__hip_bfloat16*)(ws + off); off += (size_t)NE * ND * NH * 2;
    __hip_bfloat16* w2t = (__hip_bfloat16*)(ws + off); off += (size_t)NE * NH * ND * 2;
    __hip_bfloat16* h   = (__hip_bfloat16*)(ws + off); off += (size_t)NROWS * NH * 2;
    int*   tok     = (int*)(ws + off);   off += NROWS * 4;
    float* gwb     = (float*)(ws + off); off += NROWS * 4;
    int*   cnt     = (int*)(ws + off);   off += 16 * 4;
    int*   offs    = (int*)(ws + off);   off += 16 * 4;
    int*   cursor  = (int*)(ws + off);   off += 16 * 4;
    int*   tile_e  = (int*)(ws + off);   off += MAXT * 4;
    int*   tile_row= (int*)(ws + off);   off += MAXT * 4;
    int*   ntiles  = (int*)(ws + off);   off += 16 * 4;
    (void)ws_size; (void)in_sizes; (void)n_in; (void)out_size;

    hipMemsetAsync(d_out, 0, (size_t)NB * ND * sizeof(float), stream);
    hipMemsetAsync(cnt, 0, 16 * 4, stream);

    k_cvt_x<<<dim3((NB * ND / 8 + 255) / 256), 256, 0, stream>>>(x, xb, NB * ND / 8);
    k_transpose_cvt<<<dim3(NH / 64, ND / 64, NE), 256, 0, stream>>>(w1, w1t, ND, NH);
    k_transpose_cvt<<<dim3(ND / 64, NH / 64, NE), 256, 0, stream>>>(w2, w2t, NH, ND);
    k_route_count<<<dim3((NB + 255) / 256), 256, 0, stream>>>(idx, cnt);
    k_route_scan<<<1, 64, 0, stream>>>(cnt, offs, cursor, tile_e, tile_row, ntiles);
    k_route_fill<<<dim3((NB + 255) / 256), 256, 0, stream>>>(idx, hw, cursor, tok, gwb);

    moe_gemm<1><<<dim3((NH / 128) * MAXT), 256, 0, stream>>>(
        xb, w1t, b1, h, nullptr, offs, tok, gwb, tile_e, tile_row, ntiles);
    moe_gemm<2><<<dim3((ND / 128) * MAXT), 256, 0, stream>>>(
        h, w2t, b2, nullptr, out, offs, tok, gwb, tile_e, tile_row, ntiles);
}